// Round 1
// baseline (20726.907 us; speedup 1.0000x reference)
//
#include <hip/hip_runtime.h>

typedef unsigned int u32;
typedef unsigned short u16;
typedef short bf16x8 __attribute__((ext_vector_type(8)));
typedef float f32x4 __attribute__((ext_vector_type(4)));

#define TLEN 1000
#define BATCH 128
#define IDIM 64
#define HDIM 512

#define NWG 128
#define NTHR 256

// ws byte offsets
#define H0_OFF 0
#define H1_OFF 262144
#define BAR_OFF 524288
#define PX0_OFF 525312
#define PH0_OFF 721920
#define PX1_OFF 2294784
#define PH1_OFF 3867648
#define WS_NEED 5440512

__device__ __forceinline__ u16 f2bf(float f) {
  u32 u = __float_as_uint(f);
  u += 0x7fffu + ((u >> 16) & 1u);
  return (u16)(u >> 16);
}
__device__ __forceinline__ float bf2f(u16 h) { return __uint_as_float(((u32)h) << 16); }
__device__ __forceinline__ float sigm(float x) { return 1.0f / (1.0f + __expf(-x)); }
__device__ __forceinline__ float tanhfast(float x) {
  float e = __expf(-2.0f * fabsf(x));
  float t = (1.0f - e) / (1.0f + e);
  return x >= 0.0f ? t : -t;
}
__device__ __forceinline__ void async_cp16(const void* g, void* l) {
  __builtin_amdgcn_global_load_lds((const __attribute__((address_space(1))) u32*)g,
                                   (__attribute__((address_space(3))) u32*)l, 16, 0, 0);
}

// ---------------- weight pre-pack into MFMA B-fragment order ----------------
// Frag layout: for (sl, ct, kstep): lane l holds col = ct*16+sl*16-block row
//   grow = ct*512 + sl*16 + (l&15); k = kstep*32 + (l>>4)*8 + [0..7]
__global__ void pack_weights(const float* Wih0, const float* Whh0,
                             const float* Wih1, const float* Whh1, char* ws) {
  int fid = blockIdx.x * NTHR + threadIdx.x;
  const float* src;
  int K, Kks;
  size_t obase;
  int f = fid;
  if (f < 12288) {
    src = Wih0; K = 64; Kks = 2; obase = PX0_OFF;
  } else if (f < 12288 + 98304) {
    f -= 12288; src = Whh0; K = 512; Kks = 16; obase = PH0_OFF;
  } else if (f < 12288 + 2 * 98304) {
    f -= 12288 + 98304; src = Wih1; K = 512; Kks = 16; obase = PX1_OFF;
  } else if (f < 12288 + 3 * 98304) {
    f -= 12288 + 2 * 98304; src = Whh1; K = 512; Kks = 16; obase = PH1_OFF;
  } else {
    return;
  }
  int lane = f & 63;
  int r = f >> 6;
  int ks = r % Kks; r /= Kks;
  int ct = r % 3;
  int sl = r / 3;
  int grow = ct * 512 + sl * 16 + (lane & 15);
  int k = ks * 32 + ((lane >> 4) * 8);
  const float* s = src + (size_t)grow * K + k;
  u32 p0 = f2bf(s[0]) | ((u32)f2bf(s[1]) << 16);
  u32 p1 = f2bf(s[2]) | ((u32)f2bf(s[3]) << 16);
  u32 p2 = f2bf(s[4]) | ((u32)f2bf(s[5]) << 16);
  u32 p3 = f2bf(s[6]) | ((u32)f2bf(s[7]) << 16);
  *(uint4*)(ws + obase + (size_t)fid * 0 + (size_t)f * 16) = make_uint4(p0, p1, p2, p3);
}

// ---------------- group barrier (64 wgs per batch group) ----------------
__device__ __forceinline__ void group_barrier(u32* cnt, u32* gen, u32 target) {
  __syncthreads();
  if (threadIdx.x == 0) {
    u32 old = __hip_atomic_fetch_add(cnt, 1u, __ATOMIC_ACQ_REL, __HIP_MEMORY_SCOPE_AGENT);
    if (old == 63u) {
      __hip_atomic_store(cnt, 0u, __ATOMIC_RELAXED, __HIP_MEMORY_SCOPE_AGENT);
      __hip_atomic_fetch_add(gen, 1u, __ATOMIC_RELEASE, __HIP_MEMORY_SCOPE_AGENT);
    } else {
      while (__hip_atomic_load(gen, __ATOMIC_ACQUIRE, __HIP_MEMORY_SCOPE_AGENT) < target) {
        __builtin_amdgcn_s_sleep(1);
      }
    }
  }
  __syncthreads();
}

struct KP {
  const float *x, *bih0, *bhh0, *bih1, *bhh1, *Wfc, *bfc;
  float* out;
  char* ws;
};

// K=512 phase: stage A=[64 rows][512 k] bf16 from global (swizzled source,
// linear LDS dest via global_load_lds), 2 chunks of 256 k, MFMA against pack.
__device__ __forceinline__ void h_phase(const u16* src, const bf16x8* pack, int sl, int w,
                                        int lane, char* AHp, f32x4& aR, f32x4& aZ, f32x4& a3) {
#pragma unroll 1
  for (int cb = 0; cb < 2; ++cb) {
#pragma unroll
    for (int it = 0; it < 8; ++it) {
      int slot = it * 256 + w * 64 + lane;
      int row = slot >> 5;
      int kc = slot & 31;
      int lk = kc ^ (row & 7);
      const void* g = src + (size_t)row * HDIM + cb * 256 + lk * 8;
      async_cp16(g, AHp + (it * 256 + w * 64) * 16);
    }
    __syncthreads();
    const int arow = w * 16 + (lane & 15);
#pragma unroll
    for (int ks = 0; ks < 8; ++ks) {
      int ca = ks * 4 + (lane >> 4);
      bf16x8 A = *(const bf16x8*)(AHp + arow * 512 + ((ca ^ (arow & 7)) * 16));
      int kstep = cb * 8 + ks;
      bf16x8 B0 = pack[((size_t)(sl * 3 + 0) * 16 + kstep) * 64 + lane];
      bf16x8 B1 = pack[((size_t)(sl * 3 + 1) * 16 + kstep) * 64 + lane];
      bf16x8 B2 = pack[((size_t)(sl * 3 + 2) * 16 + kstep) * 64 + lane];
      aR = __builtin_amdgcn_mfma_f32_16x16x32_bf16(A, B0, aR, 0, 0, 0);
      aZ = __builtin_amdgcn_mfma_f32_16x16x32_bf16(A, B1, aZ, 0, 0, 0);
      a3 = __builtin_amdgcn_mfma_f32_16x16x32_bf16(A, B2, a3, 0, 0, 0);
    }
    __syncthreads();
  }
}

__global__ __launch_bounds__(NTHR, 1) void gru_main(KP P) {
  __shared__ char AH[32768];
  __shared__ char AX[8192];
  const int tid = threadIdx.x;
  const int lane = tid & 63;
  const int w = tid >> 6;
  const int id = blockIdx.x;
  const int bg = id >> 6;           // batch group: 0..1 (64 rows each)
  const int layer = (id >> 5) & 1;  // 0..1
  const int sl = id & 31;           // j-slice: 16 hidden cols

  char* ws = P.ws;
  u16* h0 = (u16*)(ws + H0_OFF);
  u16* h1 = (u16*)(ws + H1_OFF);
  u32* bcnt = (u32*)(ws + BAR_OFF) + bg * 64;
  u32* bgen = bcnt + 32;
  const bf16x8* px = (const bf16x8*)(ws + (layer ? PX1_OFF : PX0_OFF));
  const bf16x8* ph = (const bf16x8*)(ws + (layer ? PH1_OFF : PH0_OFF));

  const float* bih = layer ? P.bih1 : P.bih0;
  const float* bhh = layer ? P.bhh1 : P.bhh0;
  const int jj = sl * 16 + (lane & 15);
  const float b_r = bih[jj] + bhh[jj];
  const float b_z = bih[HDIM + jj] + bhh[HDIM + jj];
  const float b_nx = bih[2 * HDIM + jj];
  const float b_nh = bhh[2 * HDIM + jj];

  u16* hout = layer ? h1 : h0;
  const size_t bgoff = (size_t)bg * 64 * HDIM;

  const f32x4 zf = {0.f, 0.f, 0.f, 0.f};
  f32x4 hown = zf;
  f32x4 aR, aZ, aN1, aN2;

#pragma unroll 1
  for (int tick = 0; tick <= TLEN; ++tick) {
    const int p = tick & 1;
    const bool active = (layer == 0) ? (tick < TLEN) : (tick >= 1);
    if (active) {
      aR = zf; aZ = zf; aN1 = zf; aN2 = zf;
      if (layer == 0) {
        // ---- x phase: stage x[bg*64+row][t][:] fp32 -> AX [64][64] bf16 (swizzled) ----
        {
          const int row = tid >> 2;
          const int part = tid & 3;
          const float* s = P.x + ((size_t)(bg * 64 + row) * TLEN + tick) * IDIM + part * 16;
          float4 v0 = ((const float4*)s)[0];
          float4 v1 = ((const float4*)s)[1];
          float4 v2 = ((const float4*)s)[2];
          float4 v3 = ((const float4*)s)[3];
          u32 p0 = f2bf(v0.x) | ((u32)f2bf(v0.y) << 16);
          u32 p1 = f2bf(v0.z) | ((u32)f2bf(v0.w) << 16);
          u32 p2 = f2bf(v1.x) | ((u32)f2bf(v1.y) << 16);
          u32 p3 = f2bf(v1.z) | ((u32)f2bf(v1.w) << 16);
          u32 p4 = f2bf(v2.x) | ((u32)f2bf(v2.y) << 16);
          u32 p5 = f2bf(v2.z) | ((u32)f2bf(v2.w) << 16);
          u32 p6 = f2bf(v3.x) | ((u32)f2bf(v3.y) << 16);
          u32 p7 = f2bf(v3.z) | ((u32)f2bf(v3.w) << 16);
          char* base = AX + row * 128;
          *(uint4*)(base + (((part * 2) ^ (row & 7)) * 16)) = make_uint4(p0, p1, p2, p3);
          *(uint4*)(base + (((part * 2 + 1) ^ (row & 7)) * 16)) = make_uint4(p4, p5, p6, p7);
        }
        __syncthreads();
        {
          const int arow = w * 16 + (lane & 15);
#pragma unroll
          for (int ks = 0; ks < 2; ++ks) {
            int ca = ks * 4 + (lane >> 4);
            bf16x8 A = *(const bf16x8*)(AX + arow * 128 + ((ca ^ (arow & 7)) * 16));
            bf16x8 B0 = px[((size_t)(sl * 3 + 0) * 2 + ks) * 64 + lane];
            bf16x8 B1 = px[((size_t)(sl * 3 + 1) * 2 + ks) * 64 + lane];
            bf16x8 B2 = px[((size_t)(sl * 3 + 2) * 2 + ks) * 64 + lane];
            aR = __builtin_amdgcn_mfma_f32_16x16x32_bf16(A, B0, aR, 0, 0, 0);
            aZ = __builtin_amdgcn_mfma_f32_16x16x32_bf16(A, B1, aZ, 0, 0, 0);
            aN1 = __builtin_amdgcn_mfma_f32_16x16x32_bf16(A, B2, aN1, 0, 0, 0);
          }
        }
        __syncthreads();
        // ---- h phase: recurrent, reads h0[1-p] ----
        const u16* hsrc = h0 + (size_t)(1 - p) * BATCH * HDIM + bgoff;
        h_phase(hsrc, ph, sl, w, lane, AH, aR, aZ, aN2);
      } else {
        // layer 1 at tick computes t = tick-1; x-input = h_seq0[t] = h0[1-p]
        const u16* xsrc = h0 + (size_t)(1 - p) * BATCH * HDIM + bgoff;
        h_phase(xsrc, px, sl, w, lane, AH, aR, aZ, aN1);
        const u16* hsrc = h1 + (size_t)(1 - p) * BATCH * HDIM + bgoff;
        h_phase(hsrc, ph, sl, w, lane, AH, aR, aZ, aN2);
      }
      // ---- gates + state update + store ----
      {
        const int jcol = sl * 16 + (lane & 15);
        u16* hw = hout + (size_t)p * BATCH * HDIM;
#pragma unroll
        for (int q = 0; q < 4; ++q) {
          float r = sigm(aR[q] + b_r);
          float z = sigm(aZ[q] + b_z);
          float n = tanhfast(aN1[q] + b_nx + r * (aN2[q] + b_nh));
          float hv = (1.f - z) * n + z * hown[q];
          hown[q] = hv;
          int rowb = bg * 64 + w * 16 + (lane >> 4) * 4 + q;
          hw[(size_t)rowb * HDIM + jcol] = f2bf(hv);
        }
      }
    }
    group_barrier(bcnt, bgen, (u32)(tick + 1));
  }

  // ---- final FC + sigmoid: hT1 = h1[parity 0] ----
  if (layer == 1 && sl == 0) {
    const u16* hT = h1;  // p=0 holds t=999
    int b = tid >> 2, qq = tid & 3;
    const u16* hr = hT + (size_t)(bg * 64 + b) * HDIM + qq * 128;
    const float* wf = P.Wfc + qq * 128;
    float s = 0.f;
#pragma unroll 4
    for (int k = 0; k < 128; ++k) s += bf2f(hr[k]) * wf[k];
    s += __shfl_xor(s, 1);
    s += __shfl_xor(s, 2);
    if (qq == 0) P.out[bg * 64 + b] = sigm(s + P.bfc[0]);
  }
}

extern "C" void kernel_launch(void* const* d_in, const int* in_sizes, int n_in,
                              void* d_out, int out_size, void* d_ws, size_t ws_size,
                              hipStream_t stream) {
  const float* x = (const float*)d_in[0];
  const float* Wih0 = (const float*)d_in[1];
  const float* Whh0 = (const float*)d_in[2];
  const float* bih0 = (const float*)d_in[3];
  const float* bhh0 = (const float*)d_in[4];
  const float* Wih1 = (const float*)d_in[5];
  const float* Whh1 = (const float*)d_in[6];
  const float* bih1 = (const float*)d_in[7];
  const float* bhh1 = (const float*)d_in[8];
  const float* Wfc = (const float*)d_in[9];
  const float* bfc = (const float*)d_in[10];

  // zero h double-buffers + barrier state (re-run every call / every replay)
  hipMemsetAsync(d_ws, 0, BAR_OFF + 1024, stream);
  pack_weights<<<dim3(1200), dim3(NTHR), 0, stream>>>(Wih0, Whh0, Wih1, Whh1, (char*)d_ws);

  KP P = {x, bih0, bhh0, bih1, bhh1, Wfc, bfc, (float*)d_out, (char*)d_ws};
  void* args[] = {&P};
  hipLaunchCooperativeKernel((void*)gru_main, dim3(NWG), dim3(NTHR), args, 0, stream);
}

// Round 4
// 12511.285 us; speedup vs baseline: 1.6567x; 1.6567x over previous
//
#include <hip/hip_runtime.h>

typedef unsigned int u32;
typedef unsigned short u16;
typedef short bf16x8 __attribute__((ext_vector_type(8)));
typedef float f32x4 __attribute__((ext_vector_type(4)));

#define TLEN 1000
#define BATCH 128
#define IDIM 64
#define HDIM 512

#define NWG 128
#define NTHR 256

// ws byte offsets
#define H0_OFF 0
#define H1_OFF 262144
#define BAR_OFF 524288
#define PX0_OFF 525312
#define PH0_OFF 721920
#define PX1_OFF 2294784
#define PH1_OFF 3867648

__device__ __forceinline__ u16 f2bf(float f) {
  u32 u = __float_as_uint(f);
  u += 0x7fffu + ((u >> 16) & 1u);
  return (u16)(u >> 16);
}
__device__ __forceinline__ float bf2f(u16 h) { return __uint_as_float(((u32)h) << 16); }
__device__ __forceinline__ float sigm(float x) { return 1.0f / (1.0f + __expf(-x)); }
__device__ __forceinline__ float tanhfast(float x) {
  float e = __expf(-2.0f * fabsf(x));
  float t = (1.0f - e) / (1.0f + e);
  return x >= 0.0f ? t : -t;
}
__device__ __forceinline__ void async_cp16(const void* g, void* l) {
  __builtin_amdgcn_global_load_lds((const __attribute__((address_space(1))) u32*)g,
                                   (__attribute__((address_space(3))) u32*)l, 16, 0, 0);
}

// ---------------- weight pre-pack into MFMA B-fragment order ----------------
__global__ void pack_weights(const float* Wih0, const float* Whh0,
                             const float* Wih1, const float* Whh1, char* ws) {
  int fid = blockIdx.x * NTHR + threadIdx.x;
  const float* src;
  int K, Kks;
  size_t obase;
  int f = fid;
  if (f < 12288) {
    src = Wih0; K = 64; Kks = 2; obase = PX0_OFF;
  } else if (f < 12288 + 98304) {
    f -= 12288; src = Whh0; K = 512; Kks = 16; obase = PH0_OFF;
  } else if (f < 12288 + 2 * 98304) {
    f -= 12288 + 98304; src = Wih1; K = 512; Kks = 16; obase = PX1_OFF;
  } else if (f < 12288 + 3 * 98304) {
    f -= 12288 + 2 * 98304; src = Whh1; K = 512; Kks = 16; obase = PH1_OFF;
  } else {
    return;
  }
  int lane = f & 63;
  int r = f >> 6;
  int ks = r % Kks; r /= Kks;
  int ct = r % 3;
  int sl = r / 3;
  int grow = ct * 512 + sl * 16 + (lane & 15);
  int k = ks * 32 + ((lane >> 4) * 8);
  const float* s = src + (size_t)grow * K + k;
  u32 p0 = f2bf(s[0]) | ((u32)f2bf(s[1]) << 16);
  u32 p1 = f2bf(s[2]) | ((u32)f2bf(s[3]) << 16);
  u32 p2 = f2bf(s[4]) | ((u32)f2bf(s[5]) << 16);
  u32 p3 = f2bf(s[6]) | ((u32)f2bf(s[7]) << 16);
  *(uint4*)(ws + obase + (size_t)f * 16) = make_uint4(p0, p1, p2, p3);
}

// ---------------- group barrier (64 wgs per batch group) ----------------
__device__ __forceinline__ void group_barrier(u32* cnt, u32* gen, u32 target) {
  __syncthreads();
  if (threadIdx.x == 0) {
    u32 old = __hip_atomic_fetch_add(cnt, 1u, __ATOMIC_ACQ_REL, __HIP_MEMORY_SCOPE_AGENT);
    if (old == 63u) {
      __hip_atomic_store(cnt, 0u, __ATOMIC_RELAXED, __HIP_MEMORY_SCOPE_AGENT);
      __hip_atomic_fetch_add(gen, 1u, __ATOMIC_RELEASE, __HIP_MEMORY_SCOPE_AGENT);
    } else {
      while (__hip_atomic_load(gen, __ATOMIC_ACQUIRE, __HIP_MEMORY_SCOPE_AGENT) < target) {
        __builtin_amdgcn_s_sleep(1);
      }
    }
  }
  __syncthreads();
}

struct KP {
  const float *x, *bih0, *bhh0, *bih1, *bhh1, *Wfc, *bfc;
  float* out;
  char* ws;
};

#define MFMA(A, B, C) __builtin_amdgcn_mfma_f32_16x16x32_bf16((A), (B), (C), 0, 0, 0)

// stage [64 rows][256 cols] chunk cb of a [64][512] bf16 slab into 32 KB of LDS.
// 16B-chunk XOR swizzle; wave-uniform dest (HW adds lane*16). Round-1 verified.
__device__ __forceinline__ void stage256(const u16* src, int cb, char* SM, int w, int lane) {
#pragma unroll
  for (int it = 0; it < 8; ++it) {
    int slot = it * 256 + w * 64 + lane;
    int row = slot >> 5;
    int kc = slot & 31;
    int lk = kc ^ (row & 7);
    async_cp16(src + (size_t)row * HDIM + cb * 256 + lk * 8, SM + (it * 256 + w * 64) * 16);
  }
}

// chunk cb holds global ksteps cb*8..cb*8+7. Wave w owns global ksteps == w (mod 4),
// i.e. local ksteps {w, w+4} -> persistent-B indices j = 2*cb, 2*cb+1 (kstep = j*4+w).
__device__ __forceinline__ void gemm_chunk(const char* SM, const bf16x8 B[3][4], int cb,
                                           int w, int lane, f32x4 a0[4], f32x4 a1[4],
                                           f32x4 a2[4]) {
#pragma unroll
  for (int j2 = 0; j2 < 2; ++j2) {
    const int j = cb * 2 + j2;
    const int lks = w + j2 * 4;
#pragma unroll
    for (int rt = 0; rt < 4; ++rt) {
      int ar = rt * 16 + (lane & 15);
      int ca = lks * 4 + (lane >> 4);
      bf16x8 A = *(const bf16x8*)(SM + ar * 512 + ((ca ^ (ar & 7)) * 16));
      a0[rt] = MFMA(A, B[0][j], a0[rt]);
      a1[rt] = MFMA(A, B[1][j], a1[rt]);
      a2[rt] = MFMA(A, B[2][j], a2[rt]);
    }
  }
}

// full K=512 GEMM: 2 staged chunks
__device__ __forceinline__ void gemm512(const u16* src, const bf16x8 B[3][4], char* SM, int w,
                                        int lane, f32x4 a0[4], f32x4 a1[4], f32x4 a2[4]) {
  stage256(src, 0, SM, w, lane);
  __syncthreads();
  gemm_chunk(SM, B, 0, w, lane, a0, a1, a2);
  __syncthreads();
  stage256(src, 1, SM, w, lane);
  __syncthreads();
  gemm_chunk(SM, B, 1, w, lane, a0, a1, a2);
  __syncthreads();
}

__global__ __launch_bounds__(NTHR, 1) void gru_main(KP P) {
  __shared__ __align__(16) char SM[40960];  // 32 KB stage chunk / 32 KB reduce overlay
  const int tid = threadIdx.x;
  const int lane = tid & 63;
  const int w = tid >> 6;  // K-quarter (interleaved ksteps == w mod 4)
  const int id = blockIdx.x;
  const int bg = id >> 6;           // batch group: 0..1 (64 rows each)
  const int layer = (id >> 5) & 1;  // 0..1
  const int sl = id & 31;           // j-slice: 16 hidden cols

  char* ws = P.ws;
  u16* h0 = (u16*)(ws + H0_OFF);
  u16* h1 = (u16*)(ws + H1_OFF);
  u32* bcnt = (u32*)(ws + BAR_OFF) + bg * 64;
  u32* bgen = bcnt + 32;
  const bf16x8* px = (const bf16x8*)(ws + (layer ? PX1_OFF : PX0_OFF));
  const bf16x8* ph = (const bf16x8*)(ws + (layer ? PH1_OFF : PH0_OFF));

  const float* bih = layer ? P.bih1 : P.bih0;
  const float* bhh = layer ? P.bhh1 : P.bhh0;
  const int jj = sl * 16 + (lane & 15);
  const float b_r = bih[jj] + bhh[jj];
  const float b_z = bih[HDIM + jj] + bhh[HDIM + jj];
  const float b_nx = bih[2 * HDIM + jj];
  const float b_nh = bhh[2 * HDIM + jj];

  u16* hout = layer ? h1 : h0;
  const size_t bgoff = (size_t)bg * 64 * HDIM;

  // ---- persistent B fragments in registers: kstep = j*4 + w ----
  bf16x8 xB[3][4], hB[3][4];
#pragma unroll
  for (int ct = 0; ct < 3; ++ct)
#pragma unroll
    for (int j = 0; j < 4; ++j)
      hB[ct][j] = ph[((size_t)(sl * 3 + ct) * 16 + (j * 4 + w)) * 64 + lane];
  if (layer == 0) {
    const bf16x8 z8 = {0, 0, 0, 0, 0, 0, 0, 0};
#pragma unroll
    for (int ct = 0; ct < 3; ++ct)
#pragma unroll
      for (int j = 0; j < 4; ++j) xB[ct][j] = z8;
    if (w < 2) {
#pragma unroll
      for (int ct = 0; ct < 3; ++ct)
        xB[ct][0] = px[((size_t)(sl * 3 + ct) * 2 + w) * 64 + lane];
    }
  } else {
#pragma unroll
    for (int ct = 0; ct < 3; ++ct)
#pragma unroll
      for (int j = 0; j < 4; ++j)
        xB[ct][j] = px[((size_t)(sl * 3 + ct) * 16 + (j * 4 + w)) * 64 + lane];
  }

  const f32x4 zf = {0.f, 0.f, 0.f, 0.f};
  f32x4 hown = zf;

#pragma unroll 1
  for (int tick = 0; tick <= TLEN; ++tick) {
    const int p = tick & 1;
    const bool active = (layer == 0) ? (tick < TLEN) : (tick >= 1);
    if (active) {
      f32x4 aR[4], aZ[4], aXN[4], aHN[4];
#pragma unroll
      for (int rt = 0; rt < 4; ++rt) { aR[rt] = zf; aZ[rt] = zf; aXN[rt] = zf; aHN[rt] = zf; }
      const u16* h0src = h0 + (size_t)(1 - p) * BATCH * HDIM + bgoff;

      if (layer == 0) {
        // overlap: issue h-stage chunk 0, then x-gemm from global (x read-only)
        stage256(h0src, 0, SM, w, lane);
        if (w < 2) {
#pragma unroll
          for (int rt = 0; rt < 4; ++rt) {
            const float* s = P.x +
                ((size_t)(bg * 64 + rt * 16 + (lane & 15)) * TLEN + tick) * IDIM +
                w * 32 + ((lane >> 4) * 8);
            float4 v0 = ((const float4*)s)[0];
            float4 v1 = ((const float4*)s)[1];
            bf16x8 A;
            A[0] = (short)f2bf(v0.x); A[1] = (short)f2bf(v0.y);
            A[2] = (short)f2bf(v0.z); A[3] = (short)f2bf(v0.w);
            A[4] = (short)f2bf(v1.x); A[5] = (short)f2bf(v1.y);
            A[6] = (short)f2bf(v1.z); A[7] = (short)f2bf(v1.w);
            aR[rt] = MFMA(A, xB[0][0], aR[rt]);
            aZ[rt] = MFMA(A, xB[1][0], aZ[rt]);
            aXN[rt] = MFMA(A, xB[2][0], aXN[rt]);
          }
        }
        __syncthreads();
        gemm_chunk(SM, hB, 0, w, lane, aR, aZ, aHN);
        __syncthreads();
        stage256(h0src, 1, SM, w, lane);
        __syncthreads();
        gemm_chunk(SM, hB, 1, w, lane, aR, aZ, aHN);
        __syncthreads();
      } else {
        const u16* h1src = h1 + (size_t)(1 - p) * BATCH * HDIM + bgoff;
        gemm512(h0src, xB, SM, w, lane, aR, aZ, aXN);  // x-input = h_seq0[t]
        gemm512(h1src, hB, SM, w, lane, aR, aZ, aHN);  // recurrent
      }

      // ---- cross-wave K reduction, 2 passes of 32 KB overlaid on SM ----
      f32x4* red = (f32x4*)SM;
#pragma unroll
      for (int rt = 0; rt < 4; ++rt) {
        red[((w * 2 + 0) * 4 + rt) * 64 + lane] = aR[rt];
        red[((w * 2 + 1) * 4 + rt) * 64 + lane] = aZ[rt];
      }
      __syncthreads();
      f32x4 R = zf, Z = zf, XN = zf, HN = zf;
#pragma unroll
      for (int kq = 0; kq < 4; ++kq) {
        R = R + red[((kq * 2 + 0) * 4 + w) * 64 + lane];
        Z = Z + red[((kq * 2 + 1) * 4 + w) * 64 + lane];
      }
      __syncthreads();
#pragma unroll
      for (int rt = 0; rt < 4; ++rt) {
        red[((w * 2 + 0) * 4 + rt) * 64 + lane] = aXN[rt];
        red[((w * 2 + 1) * 4 + rt) * 64 + lane] = aHN[rt];
      }
      __syncthreads();
#pragma unroll
      for (int kq = 0; kq < 4; ++kq) {
        XN = XN + red[((kq * 2 + 0) * 4 + w) * 64 + lane];
        HN = HN + red[((kq * 2 + 1) * 4 + w) * 64 + lane];
      }

      // ---- gates + state update + store (wave w owns row-tile w) ----
      u16* hw = hout + (size_t)p * BATCH * HDIM;
#pragma unroll
      for (int q = 0; q < 4; ++q) {
        float r = sigm(R[q] + b_r);
        float z = sigm(Z[q] + b_z);
        float n = tanhfast(XN[q] + b_nx + r * (HN[q] + b_nh));
        float hv = (1.f - z) * n + z * hown[q];
        hown[q] = hv;
        int rowb = bg * 64 + w * 16 + (lane >> 4) * 4 + q;
        hw[(size_t)rowb * HDIM + jj] = f2bf(hv);
      }
    }
    group_barrier(bcnt, bgen, (u32)(tick + 1));
  }

  // ---- final FC + sigmoid: hT1 = h1[parity 0] ----
  if (layer == 1 && sl == 0) {
    const u16* hT = h1;  // p=0 holds t=999
    int b = tid >> 2, qq = tid & 3;
    const u16* hr = hT + (size_t)(bg * 64 + b) * HDIM + qq * 128;
    const float* wf = P.Wfc + qq * 128;
    float s = 0.f;
#pragma unroll 4
    for (int k = 0; k < 128; ++k) s += bf2f(hr[k]) * wf[k];
    s += __shfl_xor(s, 1);
    s += __shfl_xor(s, 2);
    if (qq == 0) P.out[bg * 64 + b] = sigm(s + P.bfc[0]);
  }
}

extern "C" void kernel_launch(void* const* d_in, const int* in_sizes, int n_in,
                              void* d_out, int out_size, void* d_ws, size_t ws_size,
                              hipStream_t stream) {
  const float* x = (const float*)d_in[0];
  const float* Wih0 = (const float*)d_in[1];
  const float* Whh0 = (const float*)d_in[2];
  const float* bih0 = (const float*)d_in[3];
  const float* bhh0 = (const float*)d_in[4];
  const float* Wih1 = (const float*)d_in[5];
  const float* Whh1 = (const float*)d_in[6];
  const float* bih1 = (const float*)d_in[7];
  const float* bhh1 = (const float*)d_in[8];
  const float* Wfc = (const float*)d_in[9];
  const float* bfc = (const float*)d_in[10];

  hipMemsetAsync(d_ws, 0, BAR_OFF + 1024, stream);
  pack_weights<<<dim3(1200), dim3(NTHR), 0, stream>>>(Wih0, Whh0, Wih1, Whh1, (char*)d_ws);

  KP P = {x, bih0, bhh0, bih1, bhh1, Wfc, bfc, (float*)d_out, (char*)d_ws};
  void* args[] = {&P};
  hipError_t ce = hipLaunchCooperativeKernel((void*)gru_main, dim3(NWG), dim3(NTHR), args, 0,
                                             stream);
  if (ce != hipSuccess) {
    // co-residency is trivially satisfied (128 WGs, <=2 per CU footprint, 256 CUs);
    // the inter-WG barrier is hand-rolled atomics, so a plain launch is safe.
    (void)hipGetLastError();  // clear error state
    gru_main<<<dim3(NWG), dim3(NTHR), 0, stream>>>(P);
  }
}